// Round 1
// baseline (424.070 us; speedup 1.0000x reference)
//
#include <hip/hip_runtime.h>
#include <hip/hip_fp16.h>

#define MDIM 8192
#define NDIM 4096
#define KDIM 4096

typedef int v4i __attribute__((ext_vector_type(4)));
typedef int v16i __attribute__((ext_vector_type(16)));

__device__ __forceinline__ unsigned pack4(int x, int y, int z, int w) {
    return (unsigned)(x & 0xff) | ((unsigned)(y & 0xff) << 8) |
           ((unsigned)(z & 0xff) << 16) | ((unsigned)w << 24);
}

// ---- pass 1: int32 (int8-valued) -> packed int8 ----
__global__ __launch_bounds__(256) void pack_i32_to_i8(const int* __restrict__ in,
                                                      unsigned* __restrict__ out) {
    const int i = blockIdx.x * 256 + threadIdx.x;  // one group of 16 ints per thread
    const int4* p = (const int4*)in + (size_t)i * 4;
    int4 a = p[0], b = p[1], c = p[2], d = p[3];
    uint4 r;
    r.x = pack4(a.x, a.y, a.z, a.w);
    r.y = pack4(b.x, b.y, b.z, b.w);
    r.z = pack4(c.x, c.y, c.z, c.w);
    r.w = pack4(d.x, d.y, d.z, d.w);
    ((uint4*)out)[i] = r;
}

// ---- pass 2: int8 GEMM, out = x @ W^T, 128x128 tile, BK=64 ----
// 256 threads = 4 waves (2x2), each wave 64x64 out via 2x2 mfma_i32_32x32x32_i8.
// LDS rows are 64B = 4 x 16B blocks; stored block index is XOR-swizzled with
// (row>>1)&3 to spread ds_read_b128 column reads across all 32 banks. The
// swizzle is applied on the global fetch address (global_load_lds dest is
// forced to base + lane*16).
template <bool PACKED>
__global__ __launch_bounds__(256, 2) void gemm_i8(const char* __restrict__ Ap,
                                                  const char* __restrict__ Bp,
                                                  const int* __restrict__ A32,
                                                  const int* __restrict__ B32,
                                                  const _Float16* __restrict__ bias,
                                                  _Float16* __restrict__ out) {
    __shared__ char lds[16384];
    char* ldsA = lds;
    char* ldsB = lds + 8192;

    const int tid  = threadIdx.x;
    const int lane = tid & 63;
    const int wave = tid >> 6;
    const int bm0 = blockIdx.y * 128;
    const int bn0 = blockIdx.x * 128;

    // staging precompute (PACKED path): round0 covers rows 0..63, round1 +64
    const int flat = wave * 1024 + lane * 16;  // byte pos within 4KB round
    const int srow = flat >> 6;                // 0..63
    const int sblk = (flat >> 4) & 3;          // stored 16B block
    const int fblk = sblk ^ ((srow >> 1) & 3); // fetched data block (swizzle)
    int aoff = (bm0 + srow) * KDIM + fblk * 16;
    int boff = (bn0 + srow) * KDIM + fblk * 16;
    char* ldsA0 = ldsA + wave * 1024;  // wave-uniform dests
    char* ldsB0 = ldsB + wave * 1024;

    // fragment LDS addresses (constant over K loop)
    const int wm  = (wave >> 1) * 64;
    const int wn  = (wave & 1) * 64;
    const int l31 = lane & 31;
    const int kg  = lane >> 5;  // k-group 0/1
    int aaddr[2][2], baddr[2][2];
#pragma unroll
    for (int mt = 0; mt < 2; ++mt) {
        const int row = wm + mt * 32 + l31;
        const int swz = (row >> 1) & 3;
#pragma unroll
        for (int ks = 0; ks < 2; ++ks) {
            const int kb = ks * 2 + kg;
            aaddr[mt][ks] = row * 64 + ((kb ^ swz) << 4);
        }
    }
#pragma unroll
    for (int nt = 0; nt < 2; ++nt) {
        const int row = wn + nt * 32 + l31;
        const int swz = (row >> 1) & 3;
#pragma unroll
        for (int ks = 0; ks < 2; ++ks) {
            const int kb = ks * 2 + kg;
            baddr[nt][ks] = row * 64 + ((kb ^ swz) << 4);
        }
    }

    v16i acc[2][2];
#pragma unroll
    for (int mt = 0; mt < 2; ++mt)
#pragma unroll
        for (int nt = 0; nt < 2; ++nt)
#pragma unroll
            for (int i = 0; i < 16; ++i) acc[mt][nt][i] = 0;

    for (int k0 = 0; k0 < KDIM; k0 += 64) {
        if constexpr (PACKED) {
            __builtin_amdgcn_global_load_lds(
                (__attribute__((address_space(1))) void*)(Ap + aoff),
                (__attribute__((address_space(3))) void*)(ldsA0), 16, 0, 0);
            __builtin_amdgcn_global_load_lds(
                (__attribute__((address_space(1))) void*)(Ap + aoff + 64 * KDIM),
                (__attribute__((address_space(3))) void*)(ldsA0 + 4096), 16, 0, 0);
            __builtin_amdgcn_global_load_lds(
                (__attribute__((address_space(1))) void*)(Bp + boff),
                (__attribute__((address_space(3))) void*)(ldsB0), 16, 0, 0);
            __builtin_amdgcn_global_load_lds(
                (__attribute__((address_space(1))) void*)(Bp + boff + 64 * KDIM),
                (__attribute__((address_space(3))) void*)(ldsB0 + 4096), 16, 0, 0);
            aoff += 64;
            boff += 64;
        } else {
            // fallback: load int32 tiles, pack in regs, ds_write swizzled
#pragma unroll
            for (int r = 0; r < 8; ++r) {
                const int p   = r * 1024 + tid * 4;  // packed byte pos in tile
                const int row = p >> 6;
                const int kc  = p & 63;
                const int st  = row * 64 + ((((p >> 4) & 3) ^ ((row >> 1) & 3)) << 4) + (p & 15);
                int4 v = *(const int4*)(A32 + (size_t)(bm0 + row) * KDIM + k0 + kc);
                *(unsigned*)(ldsA + st) = pack4(v.x, v.y, v.z, v.w);
                int4 u = *(const int4*)(B32 + (size_t)(bn0 + row) * KDIM + k0 + kc);
                *(unsigned*)(ldsB + st) = pack4(u.x, u.y, u.z, u.w);
            }
        }
        __syncthreads();

        v4i af[2][2], bf[2][2];
#pragma unroll
        for (int mt = 0; mt < 2; ++mt)
#pragma unroll
            for (int ks = 0; ks < 2; ++ks)
                af[mt][ks] = *(const v4i*)(ldsA + aaddr[mt][ks]);
#pragma unroll
        for (int nt = 0; nt < 2; ++nt)
#pragma unroll
            for (int ks = 0; ks < 2; ++ks)
                bf[nt][ks] = *(const v4i*)(ldsB + baddr[nt][ks]);

#pragma unroll
        for (int ks = 0; ks < 2; ++ks)
#pragma unroll
            for (int mt = 0; mt < 2; ++mt)
#pragma unroll
                for (int nt = 0; nt < 2; ++nt)
                    acc[mt][nt] = __builtin_amdgcn_mfma_i32_32x32x32_i8(
                        af[mt][ks], bf[nt][ks], acc[mt][nt], 0, 0, 0);

        __syncthreads();
    }

    // epilogue: int32 -> fp16, + bias (fp16 add), C/D layout:
    // col = lane&31, row = (reg&3) + 8*(reg>>2) + 4*(lane>>5)
    const _Float16 bv0 = bias[bn0 + wn + l31];
    const _Float16 bv1 = bias[bn0 + wn + 32 + l31];
#pragma unroll
    for (int mt = 0; mt < 2; ++mt) {
#pragma unroll
        for (int nt = 0; nt < 2; ++nt) {
            const int gcol = bn0 + wn + nt * 32 + l31;
            const _Float16 bb = nt ? bv1 : bv0;
#pragma unroll
            for (int r = 0; r < 16; ++r) {
                const int rit  = (r & 3) + 8 * (r >> 2) + 4 * kg;
                const int grow = bm0 + wm + mt * 32 + rit;
                _Float16 h = (_Float16)(float)acc[mt][nt][r] + bb;
                out[(size_t)grow * NDIM + gcol] = h;
            }
        }
    }
}

extern "C" void kernel_launch(void* const* d_in, const int* in_sizes, int n_in,
                              void* d_out, int out_size, void* d_ws, size_t ws_size,
                              hipStream_t stream) {
    const int* x = (const int*)d_in[0];
    const int* w = (const int*)d_in[1];
    const _Float16* bias = (const _Float16*)d_in[2];
    _Float16* out = (_Float16*)d_out;

    const size_t xbytes = (size_t)MDIM * KDIM;  // packed int8 bytes
    const size_t wbytes = (size_t)NDIM * KDIM;

    if (ws_size >= xbytes + wbytes) {
        char* xp = (char*)d_ws;
        char* wp = xp + xbytes;
        pack_i32_to_i8<<<MDIM * KDIM / 16 / 256, 256, 0, stream>>>(x, (unsigned*)xp);
        pack_i32_to_i8<<<NDIM * KDIM / 16 / 256, 256, 0, stream>>>(w, (unsigned*)wp);
        gemm_i8<true><<<dim3(NDIM / 128, MDIM / 128), 256, 0, stream>>>(
            xp, wp, nullptr, nullptr, bias, out);
    } else {
        gemm_i8<false><<<dim3(NDIM / 128, MDIM / 128), 256, 0, stream>>>(
            nullptr, nullptr, x, w, bias, out);
    }
}

// Round 2
// 409.175 us; speedup vs baseline: 1.0364x; 1.0364x over previous
//
#include <hip/hip_runtime.h>

#define MDIM 8192
#define NDIM 4096
#define KDIM 4096
#define BM 256
#define BN 128
#define BK 64

typedef int v4i __attribute__((ext_vector_type(4)));
typedef int v16i __attribute__((ext_vector_type(16)));

__device__ __forceinline__ unsigned pack4(int x, int y, int z, int w) {
    return (unsigned)(x & 0xff) | ((unsigned)(y & 0xff) << 8) |
           ((unsigned)(z & 0xff) << 16) | ((unsigned)w << 24);
}

// ---- pass 1: int32 (int8-valued) -> packed int8 ----
__global__ __launch_bounds__(256) void pack_i32_to_i8(const int* __restrict__ in,
                                                      unsigned* __restrict__ out) {
    const int i = blockIdx.x * 256 + threadIdx.x;  // 16 ints per thread
    const int4* p = (const int4*)in + (size_t)i * 4;
    int4 a = p[0], b = p[1], c = p[2], d = p[3];
    uint4 r;
    r.x = pack4(a.x, a.y, a.z, a.w);
    r.y = pack4(b.x, b.y, b.z, b.w);
    r.z = pack4(c.x, c.y, c.z, c.w);
    r.w = pack4(d.x, d.y, d.z, d.w);
    ((uint4*)out)[i] = r;
}

// ---- pass 2: int8 GEMM, out = x @ W^T ----
// Block tile 256x128, BK=64. 256 threads = 4 waves in 2x2; each wave computes
// 128x64 via 4x2 mfma_i32_32x32x32_i8 (acc = 128 VGPR). LDS 24KB single-buffer.
// LDS rows are 64B = 4 x 16B blocks; stored block index XOR-swizzled with
// (row>>1)&3, applied on the global fetch address (global_load_lds dest is
// forced to base + lane*16).
template <bool PACKED>
__global__ __launch_bounds__(256, 2) void gemm_i8(const char* __restrict__ Ap,
                                                  const char* __restrict__ Bp,
                                                  const int* __restrict__ A32,
                                                  const int* __restrict__ B32,
                                                  const _Float16* __restrict__ bias,
                                                  _Float16* __restrict__ out) {
    __shared__ char lds[24576];
    char* ldsA = lds;           // 16 KB: 256 rows x 64 B
    char* ldsB = lds + 16384;   // 8 KB: 128 rows x 64 B

    const int tid  = threadIdx.x;
    const int lane = tid & 63;
    const int wave = tid >> 6;
    const int bm0 = blockIdx.y * BM;
    const int bn0 = blockIdx.x * BN;

    // staging: 6 chunks of 1024B per wave-issue (4 for A, 2 for B)
    int aoffs[4], boffs[2];
    char* adst[4];
    char* bdst[2];
#pragma unroll
    for (int r = 0; r < 4; ++r) {
        const int flat = (r * 4 + wave) * 1024 + lane * 16;
        const int row  = flat >> 6;
        const int fblk = ((flat >> 4) & 3) ^ ((row >> 1) & 3);
        aoffs[r] = (bm0 + row) * KDIM + fblk * 16;
        adst[r]  = ldsA + (r * 4 + wave) * 1024;
    }
#pragma unroll
    for (int r = 0; r < 2; ++r) {
        const int flat = (r * 4 + wave) * 1024 + lane * 16;
        const int row  = flat >> 6;
        const int fblk = ((flat >> 4) & 3) ^ ((row >> 1) & 3);
        boffs[r] = (bn0 + row) * KDIM + fblk * 16;
        bdst[r]  = ldsB + (r * 4 + wave) * 1024;
    }

    // fragment LDS addresses (constant over K loop)
    const int wr  = wave >> 1;   // wave row (M): 0..1
    const int wc  = wave & 1;    // wave col (N): 0..1
    const int l31 = lane & 31;
    const int kg  = lane >> 5;   // k-group 0/1
    int aaddr[4][2], baddr[2][2];
#pragma unroll
    for (int mt = 0; mt < 4; ++mt) {
        const int row = wr * 128 + mt * 32 + l31;
        const int swz = (row >> 1) & 3;
#pragma unroll
        for (int ks = 0; ks < 2; ++ks) {
            const int kb = ks * 2 + kg;
            aaddr[mt][ks] = row * 64 + ((kb ^ swz) << 4);
        }
    }
#pragma unroll
    for (int nt = 0; nt < 2; ++nt) {
        const int row = wc * 64 + nt * 32 + l31;
        const int swz = (row >> 1) & 3;
#pragma unroll
        for (int ks = 0; ks < 2; ++ks) {
            const int kb = ks * 2 + kg;
            baddr[nt][ks] = 16384 + row * 64 + ((kb ^ swz) << 4);
        }
    }

    v16i acc[4][2];
#pragma unroll
    for (int mt = 0; mt < 4; ++mt)
#pragma unroll
        for (int nt = 0; nt < 2; ++nt)
#pragma unroll
            for (int i = 0; i < 16; ++i) acc[mt][nt][i] = 0;

    for (int k0 = 0; k0 < KDIM; k0 += BK) {
        if constexpr (PACKED) {
#pragma unroll
            for (int r = 0; r < 4; ++r) {
                __builtin_amdgcn_global_load_lds(
                    (__attribute__((address_space(1))) void*)(Ap + aoffs[r]),
                    (__attribute__((address_space(3))) void*)(adst[r]), 16, 0, 0);
                aoffs[r] += BK;
            }
#pragma unroll
            for (int r = 0; r < 2; ++r) {
                __builtin_amdgcn_global_load_lds(
                    (__attribute__((address_space(1))) void*)(Bp + boffs[r]),
                    (__attribute__((address_space(3))) void*)(bdst[r]), 16, 0, 0);
                boffs[r] += BK;
            }
        } else {
            // fallback: load int32 tiles, pack in regs, write swizzled
#pragma unroll
            for (int r = 0; r < 4; ++r) {
                const int flat = (r * 4 + wave) * 1024 + lane * 16;
                const int row  = flat >> 6;
                const int fblk = ((flat >> 4) & 3) ^ ((row >> 1) & 3);
                const int* src = A32 + (size_t)(bm0 + row) * KDIM + k0 + fblk * 16;
                int4 v0 = ((const int4*)src)[0], v1 = ((const int4*)src)[1];
                int4 v2 = ((const int4*)src)[2], v3 = ((const int4*)src)[3];
                uint4 pk;
                pk.x = pack4(v0.x, v0.y, v0.z, v0.w);
                pk.y = pack4(v1.x, v1.y, v1.z, v1.w);
                pk.z = pack4(v2.x, v2.y, v2.z, v2.w);
                pk.w = pack4(v3.x, v3.y, v3.z, v3.w);
                *(uint4*)(ldsA + flat) = pk;
            }
#pragma unroll
            for (int r = 0; r < 2; ++r) {
                const int flat = (r * 4 + wave) * 1024 + lane * 16;
                const int row  = flat >> 6;
                const int fblk = ((flat >> 4) & 3) ^ ((row >> 1) & 3);
                const int* src = B32 + (size_t)(bn0 + row) * KDIM + k0 + fblk * 16;
                int4 v0 = ((const int4*)src)[0], v1 = ((const int4*)src)[1];
                int4 v2 = ((const int4*)src)[2], v3 = ((const int4*)src)[3];
                uint4 pk;
                pk.x = pack4(v0.x, v0.y, v0.z, v0.w);
                pk.y = pack4(v1.x, v1.y, v1.z, v1.w);
                pk.z = pack4(v2.x, v2.y, v2.z, v2.w);
                pk.w = pack4(v3.x, v3.y, v3.z, v3.w);
                *(uint4*)(ldsB + flat) = pk;
            }
        }
        __syncthreads();

        v4i af[4][2], bf[2][2];
#pragma unroll
        for (int mt = 0; mt < 4; ++mt)
#pragma unroll
            for (int ks = 0; ks < 2; ++ks)
                af[mt][ks] = *(const v4i*)(lds + aaddr[mt][ks]);
#pragma unroll
        for (int nt = 0; nt < 2; ++nt)
#pragma unroll
            for (int ks = 0; ks < 2; ++ks)
                bf[nt][ks] = *(const v4i*)(lds + baddr[nt][ks]);

#pragma unroll
        for (int ks = 0; ks < 2; ++ks)
#pragma unroll
            for (int mt = 0; mt < 4; ++mt)
#pragma unroll
                for (int nt = 0; nt < 2; ++nt)
                    acc[mt][nt] = __builtin_amdgcn_mfma_i32_32x32x32_i8(
                        af[mt][ks], bf[nt][ks], acc[mt][nt], 0, 0, 0);

        __syncthreads();
    }

    // epilogue: int32 -> fp16 (exact: |v|<2^24 exact in f32; larger -> f16 inf
    // either way), + bias in fp16. C/D layout: col=lane&31,
    // row=(reg&3)+8*(reg>>2)+4*(lane>>5)
    const _Float16 bv0 = bias[bn0 + wc * 64 + l31];
    const _Float16 bv1 = bias[bn0 + wc * 64 + 32 + l31];
#pragma unroll
    for (int mt = 0; mt < 4; ++mt) {
#pragma unroll
        for (int nt = 0; nt < 2; ++nt) {
            const int gcol = bn0 + wc * 64 + nt * 32 + l31;
            const _Float16 bb = nt ? bv1 : bv0;
#pragma unroll
            for (int r = 0; r < 16; ++r) {
                const int rit  = (r & 3) + 8 * (r >> 2) + 4 * kg;
                const int grow = bm0 + wr * 128 + mt * 32 + rit;
                _Float16 h = (_Float16)(float)acc[mt][nt][r] + bb;
                out[(size_t)grow * NDIM + gcol] = h;
            }
        }
    }
}

extern "C" void kernel_launch(void* const* d_in, const int* in_sizes, int n_in,
                              void* d_out, int out_size, void* d_ws, size_t ws_size,
                              hipStream_t stream) {
    const int* x = (const int*)d_in[0];
    const int* w = (const int*)d_in[1];
    const _Float16* bias = (const _Float16*)d_in[2];
    _Float16* out = (_Float16*)d_out;

    const size_t xbytes = (size_t)MDIM * KDIM;  // packed int8 bytes
    const size_t wbytes = (size_t)NDIM * KDIM;

    if (ws_size >= xbytes + wbytes) {
        char* xp = (char*)d_ws;
        char* wp = xp + xbytes;
        pack_i32_to_i8<<<MDIM * KDIM / 16 / 256, 256, 0, stream>>>(x, (unsigned*)xp);
        pack_i32_to_i8<<<NDIM * KDIM / 16 / 256, 256, 0, stream>>>(w, (unsigned*)wp);
        gemm_i8<true><<<dim3(NDIM / BN, MDIM / BM), 256, 0, stream>>>(
            xp, wp, nullptr, nullptr, bias, out);
    } else {
        gemm_i8<false><<<dim3(NDIM / BN, MDIM / BM), 256, 0, stream>>>(
            nullptr, nullptr, x, w, bias, out);
    }
}